// Round 1
// baseline (7948.325 us; speedup 1.0000x reference)
//
#include <hip/hip_runtime.h>
#include <cmath>

// Problem constants (B=2, C=64, H=W=256)
static constexpr int Bn   = 2;
static constexpr int Cn   = 64;
static constexpr int Hn   = 256;
static constexpr int Wn   = 256;
static constexpr int HW   = Hn * Wn;          // 65536
static constexpr int CHW  = Cn * HW;          // 4194304
static constexpr int NCHW = Bn * CHW;         // 8388608
static constexpr int NPIX = Bn * HW;          // 131072
static constexpr float EPSv = 1e-5f;
static constexpr float INV_N = 1.0f / 131072.0f;   // BN count = B*H*W

// ---------------------------------------------------------------------------
// Weight transpose: in[nb][oc][ic][k] -> out[nb][(ic*K+k)*OC + oc]
// (makes the OC dimension contiguous for uniform scalar loads in conv kernels)
// ---------------------------------------------------------------------------
__global__ void transpose_w_kernel(const float* __restrict__ in, float* __restrict__ out,
                                   int NB, int OC, int IC, int K) {
  int total = NB * OC * IC * K;
  for (int i = blockIdx.x * blockDim.x + threadIdx.x; i < total; i += gridDim.x * blockDim.x) {
    int k  = i % K;
    int t  = i / K;
    int ic = t % IC; t /= IC;
    int oc = t % OC;
    int nb = t / OC;
    out[(((size_t)nb * IC + ic) * K + k) * OC + oc] = in[i];
  }
}

// ---------------------------------------------------------------------------
// Prep: error = conv0(concat(Slope,Dist,Level)) (1x1), masked; x0 = ...
// ---------------------------------------------------------------------------
__global__ void prep_kernel(const float* __restrict__ LowDEM, const float* __restrict__ Point_Ele,
                            const float* __restrict__ Slope, const float* __restrict__ Distance,
                            const float* __restrict__ Level, const float* __restrict__ w0,
                            const float* __restrict__ b0, float* __restrict__ x0) {
  int i = blockIdx.x * blockDim.x + threadIdx.x;
  if (i >= NPIX) return;
  float lv  = Level[i];
  float err = w0[0] * Slope[i] + w0[1] * Distance[i] + w0[2] * lv + b0[0];
  float lm  = (lv != 0.0f) ? 1.0f : 0.0f;
  x0[i] = LowDEM[i] * (1.0f - lm) + Point_Ele[i] + err * lm;
}

// ---------------------------------------------------------------------------
// conv1: 9x9, 1 -> 64 channels, pad 4.  wT layout: [tap(81)][oc(64)]
// ---------------------------------------------------------------------------
__global__ __launch_bounds__(256, 2)
void conv9x9_kernel(const float* __restrict__ in, const float* __restrict__ wT,
                    const float* __restrict__ bias, float* __restrict__ out) {
  const int tx = threadIdx.x & 15, ty = threadIdx.x >> 4;
  const int w0 = blockIdx.x * 16, h0 = blockIdx.y * 16, b = blockIdx.z;
  __shared__ float lds[24 * 24];
  for (int idx = threadIdx.x; idx < 576; idx += 256) {
    int yy = idx / 24, xx = idx - yy * 24;
    int gy = h0 + yy - 4, gx = w0 + xx - 4;
    float v = 0.0f;
    if ((unsigned)gy < 256u && (unsigned)gx < 256u) v = in[b * HW + gy * 256 + gx];
    lds[idx] = v;
  }
  __syncthreads();
  float acc[64];
#pragma unroll
  for (int o = 0; o < 64; o++) acc[o] = 0.0f;
#pragma unroll 1
  for (int i = 0; i < 9; i++) {
#pragma unroll
    for (int j = 0; j < 9; j++) {
      float v = lds[(ty + i) * 24 + tx + j];
      const float* wp = wT + (i * 9 + j) * 64;   // uniform address -> s_load
#pragma unroll
      for (int o = 0; o < 64; o++) acc[o] = fmaf(v, wp[o], acc[o]);
    }
  }
  const int p = (h0 + ty) * 256 + (w0 + tx);
  float* op = out + (size_t)b * CHW + p;
#pragma unroll
  for (int o = 0; o < 64; o++) op[o * HW] = acc[o] + bias[o];
}

// ---------------------------------------------------------------------------
// conv3x3: 64 -> OC channels, pad 1.
// wT layout: [(ic*9+tap)*OC + oc]  (OC contiguous -> uniform scalar loads)
// BNIN==1: input is a raw conv output t; apply r = relu(t*scale+shift) on the
//          LDS staging load (zero padding applied AFTER the transform, as ref).
// ---------------------------------------------------------------------------
template <int OC, int BNIN>
__global__ __launch_bounds__(256, 2)
void conv3x3_kernel(const float* __restrict__ in, const float* __restrict__ wT,
                    const float* __restrict__ bias, const float* __restrict__ stats,
                    const float* __restrict__ g, const float* __restrict__ be,
                    float* __restrict__ out) {
  const int tx = threadIdx.x & 15, ty = threadIdx.x >> 4;
  const int w0 = blockIdx.x * 16, h0 = blockIdx.y * 16, b = blockIdx.z;
  __shared__ float lds[16][324];     // 16 channels x 18x18 tile
  __shared__ float s_sc[64], s_sh[64];
  if (BNIN) {
    if (threadIdx.x < 64) {
      int c = threadIdx.x;
      float m   = stats[c] * INV_N;
      float var = stats[64 + c] * INV_N - m * m;
      float s   = g[c] * rsqrtf(var + EPSv);
      s_sc[c] = s;
      s_sh[c] = be[c] - m * s;
    }
  }
  float acc[OC];
#pragma unroll
  for (int o = 0; o < OC; o++) acc[o] = 0.0f;
  const float* inb = in + (size_t)b * CHW;
  for (int cb = 0; cb < 64; cb += 16) {
    __syncthreads();
    for (int idx = threadIdx.x; idx < 16 * 324; idx += 256) {
      int c  = idx / 324;
      int r  = idx - c * 324;
      int yy = r / 18, xx = r - yy * 18;
      int gy = h0 + yy - 1, gx = w0 + xx - 1;
      float v = 0.0f;
      if ((unsigned)gy < 256u && (unsigned)gx < 256u) {
        v = inb[(cb + c) * HW + gy * 256 + gx];
        if (BNIN) v = fmaxf(fmaf(v, s_sc[cb + c], s_sh[cb + c]), 0.0f);
      }
      lds[c][r] = v;
    }
    __syncthreads();
#pragma unroll 1
    for (int c = 0; c < 16; c++) {
      const float* wp = wT + ((cb + c) * 9) * OC;   // uniform -> s_load
#pragma unroll
      for (int t = 0; t < 9; t++) {
        float v = lds[c][(ty + t / 3) * 18 + tx + t % 3];
#pragma unroll
        for (int o = 0; o < OC; o++) acc[o] = fmaf(v, wp[t * OC + o], acc[o]);
      }
    }
  }
  const int p = (h0 + ty) * 256 + (w0 + tx);
  float* op = out + (size_t)b * OC * HW + p;
#pragma unroll
  for (int o = 0; o < OC; o++) {
    float v = acc[o];
    if (bias) v += bias[o];
    op[o * HW] = v;
  }
}

// ---------------------------------------------------------------------------
// BN statistics: per-channel sum / sumsq over (B,H,W) -> atomics into slot
// grid (64 channels, 16 slices), block 256
// ---------------------------------------------------------------------------
__global__ void bn_stats_kernel(const float* __restrict__ t, float* __restrict__ stats) {
  const int c = blockIdx.x;
  const int slice = blockIdx.y;
  const int b = slice >> 3;
  const int hw0 = (slice & 7) * 8192;
  const float4* p = (const float4*)(t + (size_t)(b * 64 + c) * HW + hw0);
  float s = 0.0f, s2 = 0.0f;
  for (int i = threadIdx.x; i < 2048; i += 256) {
    float4 v = p[i];
    s  += v.x + v.y + v.z + v.w;
    s2 += v.x * v.x + v.y * v.y + v.z * v.z + v.w * v.w;
  }
#pragma unroll
  for (int off = 32; off > 0; off >>= 1) {
    s  += __shfl_down(s, off, 64);
    s2 += __shfl_down(s2, off, 64);
  }
  __shared__ float ls[4], ls2[4];
  const int wid = threadIdx.x >> 6;
  if ((threadIdx.x & 63) == 0) { ls[wid] = s; ls2[wid] = s2; }
  __syncthreads();
  if (threadIdx.x == 0) {
    atomicAdd(&stats[c],      ls[0] + ls[1] + ls[2] + ls[3]);
    atomicAdd(&stats[64 + c], ls2[0] + ls2[1] + ls2[2] + ls2[3]);
  }
}

// ---------------------------------------------------------------------------
// y = BN(t)*g+be + skip   (vectorized float4, scale/shift precomputed in LDS)
// ---------------------------------------------------------------------------
__global__ void bn_apply_add_kernel(const float* __restrict__ t, const float* __restrict__ stats,
                                    const float* __restrict__ g, const float* __restrict__ be,
                                    const float* __restrict__ skip, float* __restrict__ out) {
  __shared__ float s_sc[64], s_sh[64];
  if (threadIdx.x < 64) {
    int c = threadIdx.x;
    float m   = stats[c] * INV_N;
    float var = stats[64 + c] * INV_N - m * m;
    float s   = g[c] * rsqrtf(var + EPSv);
    s_sc[c] = s;
    s_sh[c] = be[c] - m * s;
  }
  __syncthreads();
  const float4* t4 = (const float4*)t;
  const float4* k4 = (const float4*)skip;
  float4* o4 = (float4*)out;
  const int n4 = NCHW / 4;
  for (int i = blockIdx.x * blockDim.x + threadIdx.x; i < n4; i += gridDim.x * blockDim.x) {
    int c = (i >> 14) & 63;     // HW/4 = 16384 vec4 per channel
    float s = s_sc[c], h = s_sh[c];
    float4 v = t4[i], kk = k4[i], r;
    r.x = fmaf(v.x, s, h) + kk.x;
    r.y = fmaf(v.y, s, h) + kk.y;
    r.z = fmaf(v.z, s, h) + kk.z;
    r.w = fmaf(v.w, s, h) + kk.w;
    o4[i] = r;
  }
}

// ---------------------------------------------------------------------------
// Deformable conv main: per-pixel, 9 taps, bilinear gather over 64 channels,
// einsum with wT[(c*9+k)*OC + oc] (uniform scalar weight loads).
// FINAL==1 (OC==1): fuse dc4 bias + conv4 1x1, write d_out (B,1,H,W).
// ---------------------------------------------------------------------------
template <int OC, int FINAL>
__global__ __launch_bounds__(256, 2)
void dcn_kernel(const float* __restrict__ x, const float* __restrict__ om,
                const float* __restrict__ wT, const float* __restrict__ bias,
                const float* __restrict__ c4w, const float* __restrict__ c4b,
                float* __restrict__ out) {
  const int tx = threadIdx.x & 15, ty = threadIdx.x >> 4;
  const int w0 = blockIdx.x * 16, h0 = blockIdx.y * 16, b = blockIdx.z;
  const int h = h0 + ty, w = w0 + tx;
  const int p = h * 256 + w;
  float acc[OC];
#pragma unroll
  for (int o = 0; o < OC; o++) acc[o] = 0.0f;
  const float* xb  = x + (size_t)b * CHW;
  const float* omb = om + (size_t)b * 27 * HW + p;
#pragma unroll 1
  for (int k = 0; k < 9; k++) {
    float dyv = omb[k * HW];
    float dxv = omb[(9 + k) * HW];
    float mo  = omb[(18 + k) * HW];
    float mk  = 1.0f / (1.0f + __expf(-mo));
    float ys = (float)(h + k / 3 - 1) + dyv;
    float xs = (float)(w + k % 3 - 1) + dxv;
    float y0f = floorf(ys), x0f = floorf(xs);
    float wy = ys - y0f, wx = xs - x0f;
    int y0 = (int)y0f, x0i = (int)x0f;
    int y1 = y0 + 1, x1 = x0i + 1;
    float vy0 = ((unsigned)y0  < 256u) ? 1.0f : 0.0f;
    float vy1 = ((unsigned)y1  < 256u) ? 1.0f : 0.0f;
    float vx0 = ((unsigned)x0i < 256u) ? 1.0f : 0.0f;
    float vx1 = ((unsigned)x1  < 256u) ? 1.0f : 0.0f;
    int cy0 = min(max(y0, 0), 255), cy1 = min(max(y1, 0), 255);
    int cx0 = min(max(x0i, 0), 255), cx1 = min(max(x1, 0), 255);
    int i00 = cy0 * 256 + cx0, i01 = cy0 * 256 + cx1;
    int i10 = cy1 * 256 + cx0, i11 = cy1 * 256 + cx1;
    float W00 = (1.0f - wy) * (1.0f - wx) * mk * vy0 * vx0;
    float W01 = (1.0f - wy) * wx * mk * vy0 * vx1;
    float W10 = wy * (1.0f - wx) * mk * vy1 * vx0;
    float W11 = wy * wx * mk * vy1 * vx1;
#pragma unroll 1
    for (int c = 0; c < 64; c++) {
      const float* xc = xb + c * HW;
      float sv = W00 * xc[i00] + W01 * xc[i01] + W10 * xc[i10] + W11 * xc[i11];
      const float* wp = wT + (c * 9 + k) * OC;   // uniform -> s_load
#pragma unroll
      for (int o = 0; o < OC; o++) acc[o] = fmaf(sv, wp[o], acc[o]);
    }
  }
  if (FINAL) {
    float v = acc[0] + bias[0];
    out[(size_t)b * HW + p] = c4w[0] * v + c4b[0];
  } else {
    float* op = out + (size_t)b * OC * HW + p;
#pragma unroll
    for (int o = 0; o < OC; o++) op[o * HW] = fmaxf(acc[o] + bias[o], 0.0f);
  }
}

// ---------------------------------------------------------------------------
extern "C" void kernel_launch(void* const* d_in, const int* in_sizes, int n_in,
                              void* d_out, int out_size, void* d_ws, size_t ws_size,
                              hipStream_t stream) {
  const float* LowDEM    = (const float*)d_in[0];
  const float* Point_Ele = (const float*)d_in[1];
  const float* Slope     = (const float*)d_in[2];
  const float* Distance  = (const float*)d_in[3];
  const float* Level     = (const float*)d_in[4];
  const float* conv0_w   = (const float*)d_in[5];
  const float* conv0_b   = (const float*)d_in[6];
  const float* conv1_w   = (const float*)d_in[7];
  const float* conv1_b   = (const float*)d_in[8];
  const float* rb_w1     = (const float*)d_in[9];
  const float* rb_g1     = (const float*)d_in[11];
  const float* rb_be1    = (const float*)d_in[12];
  const float* rb_w2     = (const float*)d_in[13];
  const float* rb_g2     = (const float*)d_in[15];
  const float* rb_be2    = (const float*)d_in[16];
  const float* conv2_w   = (const float*)d_in[17];
  const float* bn2_g     = (const float*)d_in[19];
  const float* bn2_be    = (const float*)d_in[20];
  const float* dc2_w     = (const float*)d_in[21];
  const float* dc2_b     = (const float*)d_in[22];
  const float* dc2_ow    = (const float*)d_in[23];
  const float* dc2_ob    = (const float*)d_in[24];
  const float* dc3_w     = (const float*)d_in[25];
  const float* dc3_b     = (const float*)d_in[26];
  const float* dc3_ow    = (const float*)d_in[27];
  const float* dc3_ob    = (const float*)d_in[28];
  const float* dc4_w     = (const float*)d_in[29];
  const float* dc4_b     = (const float*)d_in[30];
  const float* dc4_ow    = (const float*)d_in[31];
  const float* dc4_ob    = (const float*)d_in[32];
  const float* conv4_w   = (const float*)d_in[33];
  const float* conv4_b   = (const float*)d_in[34];

  float* Wp   = (float*)d_ws;
  float* bufX = Wp;                       // 8388608 floats each
  float* bufY = bufX + NCHW;
  float* bufT = bufY + NCHW;
  float* bufT2= bufT + NCHW;
  float* x0   = bufT2 + NCHW;             // 131072
  float* T1   = x0 + NPIX;                // 81*64   = 5184
  float* Trb1 = T1 + 5184;                // 16*576*64 = 589824
  float* Trb2 = Trb1 + 589824;
  float* Tc2  = Trb2 + 589824;            // 36864
  float* Tow2 = Tc2 + 36864;              // 576*27 = 15552
  float* Tow3 = Tow2 + 15552;
  float* Tow4 = Tow3 + 15552;
  float* Tdw2 = Tow4 + 15552;             // 36864
  float* Tdw3 = Tdw2 + 36864;
  float* stats= Tdw3 + 36864;             // 33 slots * 128 floats

  hipMemsetAsync(stats, 0, 33 * 128 * sizeof(float), stream);

  transpose_w_kernel<<<256, 256, 0, stream>>>(rb_w1,   Trb1, 16, 64, 64, 9);
  transpose_w_kernel<<<256, 256, 0, stream>>>(rb_w2,   Trb2, 16, 64, 64, 9);
  transpose_w_kernel<<<32,  256, 0, stream>>>(conv1_w, T1,    1, 64,  1, 81);
  transpose_w_kernel<<<64,  256, 0, stream>>>(conv2_w, Tc2,   1, 64, 64, 9);
  transpose_w_kernel<<<32,  256, 0, stream>>>(dc2_ow,  Tow2,  1, 27, 64, 9);
  transpose_w_kernel<<<32,  256, 0, stream>>>(dc3_ow,  Tow3,  1, 27, 64, 9);
  transpose_w_kernel<<<32,  256, 0, stream>>>(dc4_ow,  Tow4,  1, 27, 64, 9);
  transpose_w_kernel<<<64,  256, 0, stream>>>(dc2_w,   Tdw2,  1, 64, 64, 9);
  transpose_w_kernel<<<64,  256, 0, stream>>>(dc3_w,   Tdw3,  1, 64, 64, 9);

  prep_kernel<<<(NPIX + 255) / 256, 256, 0, stream>>>(LowDEM, Point_Ele, Slope, Distance,
                                                      Level, conv0_w, conv0_b, x0);

  dim3 grid16(16, 16, 2);
  dim3 sgrid(64, 16);

  conv9x9_kernel<<<grid16, 256, 0, stream>>>(x0, T1, conv1_b, bufX);   // X in bufX

  for (int i = 0; i < 16; i++) {
    const float* src = (i == 0) ? bufX : bufY;
    // t1 = conv(y, w1)  (bias dropped: cancelled by BN)
    conv3x3_kernel<64, 0><<<grid16, 256, 0, stream>>>(src, Trb1 + (size_t)i * 36864,
                                                      nullptr, nullptr, nullptr, nullptr, bufT);
    bn_stats_kernel<<<sgrid, 256, 0, stream>>>(bufT, stats + (2 * i) * 128);
    // t2 = conv(relu(bn(t1)), w2)   (bn+relu fused into staging load)
    conv3x3_kernel<64, 1><<<grid16, 256, 0, stream>>>(bufT, Trb2 + (size_t)i * 36864,
                                                      nullptr, stats + (2 * i) * 128,
                                                      rb_g1 + i * 64, rb_be1 + i * 64, bufT2);
    bn_stats_kernel<<<sgrid, 256, 0, stream>>>(bufT2, stats + (2 * i + 1) * 128);
    // y = bn(t2) + y
    bn_apply_add_kernel<<<2048, 256, 0, stream>>>(bufT2, stats + (2 * i + 1) * 128,
                                                  rb_g2 + i * 64, rb_be2 + i * 64, src, bufY);
  }

  // x = bn(conv2(y)) + x    -> bufX
  conv3x3_kernel<64, 0><<<grid16, 256, 0, stream>>>(bufY, Tc2, nullptr, nullptr, nullptr, nullptr, bufT);
  bn_stats_kernel<<<sgrid, 256, 0, stream>>>(bufT, stats + 32 * 128);
  bn_apply_add_kernel<<<2048, 256, 0, stream>>>(bufT, stats + 32 * 128, bn2_g, bn2_be, bufX, bufX);

  // dc2: x = relu(dcn(x)) -> bufY
  conv3x3_kernel<27, 0><<<grid16, 256, 0, stream>>>(bufX, Tow2, dc2_ob, nullptr, nullptr, nullptr, bufT);
  dcn_kernel<64, 0><<<grid16, 256, 0, stream>>>(bufX, bufT, Tdw2, dc2_b, nullptr, nullptr, bufY);

  // dc3: x = relu(dcn(x)) -> bufX
  conv3x3_kernel<27, 0><<<grid16, 256, 0, stream>>>(bufY, Tow3, dc3_ob, nullptr, nullptr, nullptr, bufT);
  dcn_kernel<64, 0><<<grid16, 256, 0, stream>>>(bufY, bufT, Tdw3, dc3_b, nullptr, nullptr, bufX);

  // dc4 + conv4 (fused) -> d_out
  conv3x3_kernel<27, 0><<<grid16, 256, 0, stream>>>(bufX, Tow4, dc4_ob, nullptr, nullptr, nullptr, bufT);
  dcn_kernel<1, 1><<<grid16, 256, 0, stream>>>(bufX, bufT, dc4_w, dc4_b, conv4_w, conv4_b, (float*)d_out);
}